// Round 7
// baseline (101.014 us; speedup 1.0000x reference)
//
#include <hip/hip_runtime.h>

// Bit-replicate the fp32 reference. Evidence lineage (absmax vs ref):
//   exact fp64                              0.96
//   CR cube, seq sum, seq prod              0.62  -> cube is a mul-chain
//   mul cube, seq sum, seq prod             0.43
//   mul cube, fma-seq sum, seq prod         0.51  -> no fma in reduce
//   mul cube, T1 sum, seq prod              0.36  -> shuffle-halves shape
//   mul cube, T3 sum, TREE prod             0.80  -> tree prod is WRONG
// Two-noise-model fit over all 5 points => ref = T3 sum + SEQUENTIAL prod
// (R6's regression was entirely the prod tree; T3 = masked/tail-folded
// SIMD reduce shape: acc=[m0+m4,m1,m2,m3] -> ((m0+m4)+m2)+(m1+m3)).
#pragma clang fp contract(off)

#define FEATURES   512
#define N_BSPLINES 64
#define N_KNOTS    68   // N_BSPLINES + DEGREE + 1
#define WINDOW     5    // DEGREE + 2
#define BATCH      2048

#define TILE_F 16
#define TILE_B 64
#define QPT    4        // outputs per thread = TILE_B / 16
#define NTHREADS 256

__device__ __forceinline__ float cube_f32(float r) {
    float s = r * r;
    return s * r;
}

__global__ __launch_bounds__(NTHREADS) void bspline_fused(
    const float* __restrict__ x, const float* __restrict__ knots,
    const float* __restrict__ weights, float* __restrict__ out)
{
    // [t][ft] layouts: 16 consecutive floats per row -> conflict-free broadcast reads
    __shared__ float kL[N_KNOTS * TILE_F];
    __shared__ float wL[N_BSPLINES * TILE_F];
    __shared__ float cL[N_BSPLINES * WINDOW * TILE_F];

    const int tid = threadIdx.x;
    const int f0  = (blockIdx.x & (FEATURES / TILE_F - 1)) * TILE_F;
    const int b0  = (blockIdx.x / (FEATURES / TILE_F)) * TILE_B;

    for (int e = tid; e < TILE_F * N_KNOTS; e += NTHREADS) {
        int ft = e / N_KNOTS, t = e % N_KNOTS;
        kL[t * TILE_F + ft] = knots[(f0 + ft) * N_KNOTS + t];
    }
    for (int e = tid; e < TILE_F * N_BSPLINES; e += NTHREADS) {
        int ft = e / N_BSPLINES, i = e % N_BSPLINES;
        wL[i * TILE_F + ft] = weights[(f0 + ft) * N_BSPLINES + i];
    }
    __syncthreads();

    // coef[i][j] = 1 / prod_{b=0..4} ((k[i+b]-k[i+j]) + eye[j][b])
    // SEQUENTIAL ascending fp32 product (b==j factor is exact 1.0), IEEE divide.
    for (int e = tid; e < TILE_F * N_BSPLINES * WINDOW; e += NTHREADS) {
        int ft = e / (N_BSPLINES * WINDOW);
        int m  = e % (N_BSPLINES * WINDOW);
        int i = m / WINDOW, j = m % WINDOW;
        float kj = kL[(i + j) * TILE_F + ft];
        float prod = 1.0f;
        #pragma unroll
        for (int b = 0; b < WINDOW; ++b) {
            float df = (b == j) ? 1.0f : (kL[(i + b) * TILE_F + ft] - kj);
            prod = prod * df;
        }
        cL[m * TILE_F + ft] = 1.0f / prod;
    }
    __syncthreads();

    const int ft = tid & (TILE_F - 1);
    const int bt = tid >> 4;

    float xq[QPT], acc[QPT];
    float r0[QPT], r1[QPT], r2[QPT], r3[QPT], r4[QPT];
    #pragma unroll
    for (int q = 0; q < QPT; ++q) {
        int b = b0 + bt + 16 * q;
        xq[q]  = x[b * FEATURES + f0 + ft];
        acc[q] = 0.0f;
        r0[q] = cube_f32(fmaxf(xq[q] - kL[0 * TILE_F + ft], 0.0f));
        r1[q] = cube_f32(fmaxf(xq[q] - kL[1 * TILE_F + ft], 0.0f));
        r2[q] = cube_f32(fmaxf(xq[q] - kL[2 * TILE_F + ft], 0.0f));
        r3[q] = cube_f32(fmaxf(xq[q] - kL[3 * TILE_F + ft], 0.0f));
        r4[q] = cube_f32(fmaxf(xq[q] - kL[4 * TILE_F + ft], 0.0f));
    }

    for (int i = 0; i < N_BSPLINES; ++i) {
        const float c0 = cL[(i * WINDOW + 0) * TILE_F + ft];
        const float c1 = cL[(i * WINDOW + 1) * TILE_F + ft];
        const float c2 = cL[(i * WINDOW + 2) * TILE_F + ft];
        const float c3 = cL[(i * WINDOW + 3) * TILE_F + ft];
        const float c4 = cL[(i * WINDOW + 4) * TILE_F + ft];
        const float wi = wL[i * TILE_F + ft];
        #pragma unroll
        for (int q = 0; q < QPT; ++q) {
            float m0 = r0[q] * c0;
            float m1 = r1[q] * c1;
            float m2 = r2[q] * c2;
            float m3 = r3[q] * c3;
            float m4 = r4[q] * c4;
            // T3: masked-tail fold of m4 into lane 0, then shuffle-halves:
            float t04  = m0 + m4;
            float t042 = t04 + m2;
            float t13  = m1 + m3;
            float sp   = t042 + t13;
            acc[q] = acc[q] + sp * wi;    // unfused, sequential i-sum (O(1) scale)
            // slide the truncated-power window: one new cube per spline
            r0[q] = r1[q]; r1[q] = r2[q]; r2[q] = r3[q]; r3[q] = r4[q];
        }
        if (i < N_BSPLINES - 1) {
            #pragma unroll
            for (int q = 0; q < QPT; ++q)
                r4[q] = cube_f32(fmaxf(xq[q] - kL[(i + 5) * TILE_F + ft], 0.0f));
        }
    }

    #pragma unroll
    for (int q = 0; q < QPT; ++q) {
        int b = b0 + bt + 16 * q;
        out[b * FEATURES + f0 + ft] = acc[q];
    }
}

extern "C" void kernel_launch(void* const* d_in, const int* in_sizes, int n_in,
                              void* d_out, int out_size, void* d_ws, size_t ws_size,
                              hipStream_t stream) {
    const float* x       = (const float*)d_in[0];   // (2048, 512)
    const float* knots   = (const float*)d_in[1];   // (512, 68)
    const float* weights = (const float*)d_in[2];   // (512, 64)
    float*       out     = (float*)d_out;           // (2048, 512)

    const int blocks = (FEATURES / TILE_F) * (BATCH / TILE_B);   // 32*32 = 1024
    bspline_fused<<<blocks, NTHREADS, 0, stream>>>(x, knots, weights, out);
}

// Round 8
// 84.950 us; speedup vs baseline: 1.1891x; 1.1891x over previous
//
#include <hip/hip_runtime.h>

// Bit-exact recipe (locked by R1-R7 bisection, absmax 0.0078 vs 0.106 thr):
//   cube  = (x*x)*x ;  j-sum = T3  ((m0+m4)+m2)+(m1+m3) ;  no fma anywhere
//   coef  = sequential ascending fp32 prod (b==j -> 1.0), IEEE divide
//   i-sum = sequential ascending, unfused mul/add
// R7 counters: VALUBusy 62%, Occ 30%, 6.5M LDS bank conflicts, HBM 2%.
// This round: block-uniform feature -> knots/coef/weights via SGPR s_load,
// zero LDS, 4x grid, full i-unroll (slide window becomes SSA renaming).
#pragma clang fp contract(off)

#define FEATURES   512
#define N_BSPLINES 64
#define N_KNOTS    68   // N_BSPLINES + DEGREE + 1
#define WINDOW     5    // DEGREE + 2
#define BATCH      2048

__device__ __forceinline__ float cube_f32(float r) {
    float s = r * r;
    return s * r;
}

// One block per feature, one thread per (i,j): bit-identical coef table.
__global__ __launch_bounds__(N_BSPLINES * WINDOW) void bspline_prep(
    const float* __restrict__ knots, float* __restrict__ coef)
{
    const int f = blockIdx.x;
    const int t = threadIdx.x;             // t = i*WINDOW + j
    const int i = t / WINDOW, j = t % WINDOW;
    const float* kf = knots + f * N_KNOTS;
    const float kj = kf[i + j];
    float prod = 1.0f;
    #pragma unroll
    for (int b = 0; b < WINDOW; ++b) {
        float df = (b == j) ? 1.0f : (kf[i + b] - kj);
        prod = prod * df;                  // sequential ascending, fp32
    }
    coef[f * (N_BSPLINES * WINDOW) + t] = 1.0f / prod;
}

// Block = one feature x 256 batch rows. f is blockIdx-derived -> all
// knots/coef/weights indices are wave-uniform -> compiler emits s_load
// (SGPR operands, no LDS, no bank conflicts, ~zero latency exposure).
__global__ __launch_bounds__(256, 8) void bspline_eval(
    const float* __restrict__ x, const float* __restrict__ knots,
    const float* __restrict__ coef, const float* __restrict__ weights,
    float* __restrict__ out)
{
    const int f  = blockIdx.x & (FEATURES - 1);       // uniform per block
    const int bc = blockIdx.x >> 9;                   // batch chunk 0..7
    const int b  = bc * 256 + threadIdx.x;

    const float* __restrict__ kf = knots   + f * N_KNOTS;
    const float* __restrict__ cf = coef    + f * (N_BSPLINES * WINDOW);
    const float* __restrict__ wf = weights + f * N_BSPLINES;

    const float xv = x[b * FEATURES + f];             // stride-512; L2 absorbs
    float acc = 0.0f;
    float r0 = cube_f32(fmaxf(xv - kf[0], 0.0f));
    float r1 = cube_f32(fmaxf(xv - kf[1], 0.0f));
    float r2 = cube_f32(fmaxf(xv - kf[2], 0.0f));
    float r3 = cube_f32(fmaxf(xv - kf[3], 0.0f));
    float r4 = cube_f32(fmaxf(xv - kf[4], 0.0f));

    #pragma unroll
    for (int i = 0; i < N_BSPLINES; ++i) {
        float m0 = r0 * cf[i * WINDOW + 0];
        float m1 = r1 * cf[i * WINDOW + 1];
        float m2 = r2 * cf[i * WINDOW + 2];
        float m3 = r3 * cf[i * WINDOW + 3];
        float m4 = r4 * cf[i * WINDOW + 4];
        // T3: masked-tail fold of m4 into lane 0, then shuffle-halves
        float t04  = m0 + m4;
        float t042 = t04 + m2;
        float t13  = m1 + m3;
        float sp   = t042 + t13;
        acc = acc + sp * wf[i];           // unfused, sequential i-sum
        r0 = r1; r1 = r2; r2 = r3; r3 = r4;   // SSA-renamed by full unroll
        if (i < N_BSPLINES - 1)
            r4 = cube_f32(fmaxf(xv - kf[i + 5], 0.0f));
    }

    out[b * FEATURES + f] = acc;
}

extern "C" void kernel_launch(void* const* d_in, const int* in_sizes, int n_in,
                              void* d_out, int out_size, void* d_ws, size_t ws_size,
                              hipStream_t stream) {
    const float* x       = (const float*)d_in[0];   // (2048, 512)
    const float* knots   = (const float*)d_in[1];   // (512, 68)
    const float* weights = (const float*)d_in[2];   // (512, 64)
    float*       out     = (float*)d_out;           // (2048, 512)
    float*       coef    = (float*)d_ws;            // 512*320 floats = 640 KiB

    bspline_prep<<<FEATURES, N_BSPLINES * WINDOW, 0, stream>>>(knots, coef);

    const int blocks = FEATURES * (BATCH / 256);    // 512 * 8 = 4096
    bspline_eval<<<blocks, 256, 0, stream>>>(x, knots, coef, weights, out);
}